// Round 5
// baseline (175.009 us; speedup 1.0000x reference)
//
#include <hip/hip_runtime.h>
#include <hip/hip_bf16.h>

#define IN_EPS 1e-5f

typedef __attribute__((ext_vector_type(8))) short short8;
typedef __attribute__((ext_vector_type(4))) float f32x4;

__device__ __forceinline__ short f2bf(float f) {
  __hip_bfloat16 h = (__hip_bfloat16)f;   // lowers to v_cvt_pk_bf16_f32
  return *(short*)&h;
}

__device__ __forceinline__ void glds16(const void* g, void* l) {
  typedef const __attribute__((address_space(1))) void gconst_t;
  typedef __attribute__((address_space(3))) void lds_t;
  __builtin_amdgcn_global_load_lds((gconst_t*)g, (lds_t*)l, 16, 0, 0);
}

// ---------------------------------------------------------------------------
// Weight conversion: f32 [O][C][3][3] -> bf16 swizzled panel image.
// Panel p = mblk*36 + cblk*9 + tap holds [o_local 128][c_local 64], elem at
//   (p<<13) + (ol<<6) + (cl ^ ((ol&7)<<3))
// ---------------------------------------------------------------------------
__global__ void wconv_k(const float* __restrict__ src, short* __restrict__ dst,
                        int O) {
  int idx = blockIdx.x * 256 + threadIdx.x;
  if (idx >= O * 2304) return;
  int o = idx / 2304;
  int r = idx - o * 2304;
  int c = r / 9;
  int k = r - c * 9;
  int mblk = o >> 7, ol = o & 127, cb = c >> 6, cl = c & 63;
  dst[(((size_t)(mblk * 36 + cb * 9 + k)) << 13) + (ol << 6) + (cl ^ ((ol & 7) << 3))]
      = f2bf(src[idx]);
}

// ---------------------------------------------------------------------------
// Adaptive Gaussian kernel: kern[b][k][h][w] = exp(-0.5 * sum_c dg^2)
// lane == image col; neighbors via shfl; no barriers in the channel loop.
// ---------------------------------------------------------------------------
__global__ __launch_bounds__(256) void kern_k(const float* __restrict__ g,
                                              float* __restrict__ kern) {
  int h = blockIdx.x, b = blockIdx.y;
  int t = threadIdx.x, w = t & 63, cg = t >> 6;
  float acc[9];
#pragma unroll
  for (int k = 0; k < 9; ++k) acc[k] = 0.f;
  const float* base = g + (((size_t)b * 256 + (cg << 6)) << 12) + (h << 6) + w;
#pragma unroll 4
  for (int cc = 0; cc < 64; ++cc) {
    const float* gp = base + ((size_t)cc << 12);
    float mid = gp[0];
    float top = (h > 0) ? gp[-64] : 0.f;
    float bot = (h < 63) ? gp[64] : 0.f;
    float rows[3] = {top, mid, bot};
#pragma unroll
    for (int i = 0; i < 3; ++i) {
      float v = rows[i];
      float l = __shfl_up(v, 1);
      float r = __shfl_down(v, 1);
      if (w == 0) l = 0.f;
      if (w == 63) r = 0.f;
      float dl = l - mid, dm = v - mid, dr = r - mid;
      acc[i * 3 + 0] += dl * dl;
      acc[i * 3 + 1] += dm * dm;
      acc[i * 3 + 2] += dr * dr;
    }
  }
  __shared__ float red[4][9][64];
#pragma unroll
  for (int k = 0; k < 9; ++k) red[cg][k][w] = acc[k];
  __syncthreads();
  for (int idx = t; idx < 576; idx += 256) {
    int k = idx >> 6, w2 = idx & 63;
    float s = red[0][k][w2] + red[1][k][w2] + red[2][k][w2] + red[3][k][w2];
    kern[(((size_t)b * 9 + k) << 12) + (h << 6) + w2] = expf(-0.5f * s);
  }
}

// ---------------------------------------------------------------------------
// Implicit-GEMM conv with tap-reuse. BM=128, BN=128 (2 rows), 512 thr/8 waves
// (2M x 4N, wave tile 64x32). K order: 4 c-blocks x 9 taps.
// A: double-buffered LDS, staged via global_load_lds from the pre-swizzled
//    panel image (1 barrier/step; glds flight hidden under compute).
// B: halo [4 rows][64 cols][64 ch] staged once per c-block (T14 split: loads
//    issued before the boundary tap's compute, cvt+write after the barrier).
// GEMM1: per-tap partial, acc += kern[tap,px] * part (f32 VALU epilogue).
// GEMM2: instance-norm+relu fused into B staging.
// ---------------------------------------------------------------------------
template <int MBLKS, bool USE_KERN, bool USE_NORM>
__global__ __launch_bounds__(512, 4) void gemm_conv(
    const short* __restrict__ Wimg, const float* __restrict__ X,
    const float* __restrict__ Kf, const float* __restrict__ MRin,
    float* __restrict__ out) {
  constexpr int MOUT = MBLKS * 128;
  __shared__ short ldsA[2][8192];           // [o 128][c 64] swizzled, dbuf
  __shared__ short ldsB[4 * 64 * 64];       // [r 4][col 64][c 64] swizzled
  __shared__ short ldsS[4 * 2 * 64];        // side halo cols (-1,64): zeros
  __shared__ float klds[USE_KERN ? 9 * 128 : 1];

  const int t = threadIdx.x;
  const int nblk = blockIdx.x, mblk = blockIdx.y, b = blockIdx.z;
  const int h0 = nblk * 2;
  const int lane = t & 63, wid = t >> 6;
  const int wr = wid >> 2, wc = wid & 3;
  const int fr = lane & 15, kg = (lane >> 4) << 3;
  const int scol = t & 63;        // B staging: image col
  const int c8 = (t >> 6) << 3;   // B staging: 8-channel base

  f32x4 acc[4][2];
#pragma unroll
  for (int i = 0; i < 4; ++i)
#pragma unroll
    for (int j = 0; j < 2; ++j) acc[i][j] = {0.f, 0.f, 0.f, 0.f};

  float breg[4][8];
  float2 mreg[8];

  auto stageA = [&](int step, int buf) {
    const short* src = Wimg + (((size_t)(mblk * 36 + step)) << 13);
#pragma unroll
    for (int i = 0; i < 2; ++i)
      glds16(src + (((i << 9) + t) << 3),
             &ldsA[buf][((i << 9) + (wid << 6)) << 3]);
  };
  auto loadBregs = [&](int cbn) {
    int c0 = cbn << 6;
    const float* base = X + (((size_t)b * 256 + c0 + c8) << 12) + scol;
    if (USE_NORM) {
#pragma unroll
      for (int i = 0; i < 8; ++i)
        mreg[i] = ((const float2*)MRin)[b * 256 + c0 + c8 + i];
    }
#pragma unroll
    for (int r = 0; r < 4; ++r) {
      int hr = h0 - 1 + r;
      bool okr = (unsigned)hr < 64u;
      const float* src = base + (hr << 6);
#pragma unroll
      for (int i = 0; i < 8; ++i)
        breg[r][i] = okr ? src[(size_t)i << 12] : 0.f;
    }
  };
  auto writeB = [&]() {
#pragma unroll
    for (int r = 0; r < 4; ++r) {
      short8 pk;
#pragma unroll
      for (int i = 0; i < 8; ++i) {
        float x = breg[r][i];
        if (USE_NORM) x = fmaxf((x - mreg[i].x) * mreg[i].y, 0.f);
        pk[i] = f2bf(x);
      }
      *(short8*)&ldsB[(((r << 6) + scol) << 6) + (c8 ^ ((scol & 7) << 3))] = pk;
    }
  };
  auto computeTap = [&](int tap, int buf) {
    const short* As = ldsA[buf];
    const int di = tap / 3 - 1, dj = tap % 3 - 1;
    f32x4 part[4][2];
    if (USE_KERN) {
#pragma unroll
      for (int i = 0; i < 4; ++i)
#pragma unroll
        for (int j = 0; j < 2; ++j) part[i][j] = {0.f, 0.f, 0.f, 0.f};
    }
    f32x4(&dst)[4][2] = *(USE_KERN ? &part : &acc);
#pragma unroll
    for (int ks = 0; ks < 2; ++ks) {
      int kb = (ks << 5) + kg;
      short8 a4[4], b2[2];
#pragma unroll
      for (int mf = 0; mf < 4; ++mf) {
        int rr = (wr << 6) + (mf << 4) + fr;
        a4[mf] = *(const short8*)&As[(rr << 6) + (kb ^ ((rr & 7) << 3))];
      }
#pragma unroll
      for (int nf = 0; nf < 2; ++nf) {
        int px = (wc << 5) + (nf << 4) + fr;
        int rr2 = (px >> 6) + di + 1;
        int wcol = (px & 63) + dj;
        int kbs = kb ^ ((wcol & 7) << 3);
        const short* pm = &ldsB[(((rr2 << 6) + wcol) << 6) + kbs];
        const short* ps = &ldsS[(((rr2 << 1) + (wcol == 64)) << 6) + kbs];
        b2[nf] = *(const short8*)(((unsigned)wcol < 64u) ? pm : ps);
      }
      __builtin_amdgcn_s_setprio(1);
#pragma unroll
      for (int mf = 0; mf < 4; ++mf)
#pragma unroll
        for (int nf = 0; nf < 2; ++nf)
          dst[mf][nf] = __builtin_amdgcn_mfma_f32_16x16x32_bf16(
              a4[mf], b2[nf], dst[mf][nf], 0, 0, 0);
      __builtin_amdgcn_s_setprio(0);
    }
    if (USE_KERN) {
      float kq0 = klds[tap * 128 + (wc << 5) + fr];
      float kq1 = klds[tap * 128 + (wc << 5) + 16 + fr];
#pragma unroll
      for (int mf = 0; mf < 4; ++mf)
#pragma unroll
        for (int j = 0; j < 4; ++j) {
          acc[mf][0][j] += kq0 * part[mf][0][j];
          acc[mf][1][j] += kq1 * part[mf][1][j];
        }
    }
  };

  // ---- prologue ----
  if (t < 64) {
    short8 z = {0, 0, 0, 0, 0, 0, 0, 0};
    *(short8*)&ldsS[t << 3] = z;
  }
  if (USE_KERN) {
    for (int idx = t; idx < 1152; idx += 512) {
      int tap = idx >> 7, px = idx & 127;
      klds[idx] = Kf[(((size_t)b * 9 + tap) << 12) +
                     ((h0 + (px >> 6)) << 6) + (px & 63)];
    }
  }
  stageA(0, 0);
  loadBregs(0);
  writeB();
  __syncthreads();   // drains vmcnt -> A(0) landed; publishes B

  // ---- main loop: 4 c-blocks x 9 taps, dbuf A, 1 barrier/step ----
  int cb = 0, tap = 0;
  for (int step = 0; step < 36; ++step) {
    int cur = step & 1, nxt = cur ^ 1;
    bool more = (step + 1) < 36;
    bool lastTap = (tap == 8);
    if (more) stageA(step + 1, nxt);          // async glds, flies under compute
    if (more && lastTap) loadBregs(cb + 1);   // T14: issue loads early
    computeTap(tap, cur);
    if (more && lastTap) {
      __syncthreads();                        // all waves done reading old B
      writeB();                               // norm+cvt+write
    }
    __syncthreads();                          // publish A(nxt) (+B)
    if (++tap == 9) { tap = 0; ++cb; }
  }

  // ---- epilogue ----
  const int row4 = (lane >> 4) << 2;
#pragma unroll
  for (int mf = 0; mf < 4; ++mf) {
    int o = (mblk << 7) + (wr << 6) + (mf << 4) + row4;
    size_t ob = (((size_t)b * MOUT + o) << 12) + (nblk << 7) + (wc << 5) + fr;
#pragma unroll
    for (int nf = 0; nf < 2; ++nf) {
      f32x4 v = acc[mf][nf];
      size_t oo = ob + (nf << 4);
      out[oo] = v[0];
      out[oo + 4096] = v[1];
      out[oo + 8192] = v[2];
      out[oo + 12288] = v[3];
    }
  }
}

// ---------------------------------------------------------------------------
// per-(b,ch) mean / rstd over 4096 pixels
// ---------------------------------------------------------------------------
__global__ __launch_bounds__(256) void reduce_mv(const float* __restrict__ x,
                                                 float* __restrict__ mr) {
  int bc = blockIdx.x, t = threadIdx.x;
  const float4* xp = (const float4*)(x + ((size_t)bc << 12));
  float s = 0.f, s2 = 0.f;
  for (int i = t; i < 1024; i += 256) {
    float4 v = xp[i];
    s += v.x + v.y + v.z + v.w;
    s2 += v.x * v.x + v.y * v.y + v.z * v.z + v.w * v.w;
  }
#pragma unroll
  for (int off = 32; off; off >>= 1) {
    s += __shfl_down(s, off);
    s2 += __shfl_down(s2, off);
  }
  __shared__ float ls[4], ls2[4];
  int wid = t >> 6, lane = t & 63;
  if (!lane) { ls[wid] = s; ls2[wid] = s2; }
  __syncthreads();
  if (!t) {
    s = ls[0] + ls[1] + ls[2] + ls[3];
    s2 = ls2[0] + ls2[1] + ls2[2] + ls2[3];
    float m = s * (1.f / 4096.f);
    float var = s2 * (1.f / 4096.f) - m * m;
    mr[2 * bc] = m;
    mr[2 * bc + 1] = rsqrtf(fmaxf(var, 0.f) + IN_EPS);
  }
}

// ---------------------------------------------------------------------------
// out = relu((y - mean)*rstd), float4 over [8*128*4096]
// ---------------------------------------------------------------------------
__global__ __launch_bounds__(256) void finalize_k(const float* __restrict__ y,
                                                  const float* __restrict__ mr,
                                                  float* __restrict__ out) {
  int i = blockIdx.x * 256 + threadIdx.x;
  int bc = i >> 10;
  float m = mr[2 * bc], r = mr[2 * bc + 1];
  float4 v = ((const float4*)y)[i];
  v.x = fmaxf((v.x - m) * r, 0.f);
  v.y = fmaxf((v.y - m) * r, 0.f);
  v.z = fmaxf((v.z - m) * r, 0.f);
  v.w = fmaxf((v.w - m) * r, 0.f);
  ((float4*)out)[i] = v;
}

extern "C" void kernel_launch(void* const* d_in, const int* in_sizes, int n_in,
                              void* d_out, int out_size, void* d_ws,
                              size_t ws_size, hipStream_t stream) {
  (void)in_sizes; (void)n_in; (void)out_size; (void)ws_size;
  const float* feat  = (const float*)d_in[0];
  const float* guide = (const float*)d_in[1];
  const float* pac_w = (const float*)d_in[2];
  const float* dec_w = (const float*)d_in[3];
  // d_in[4] (dec_b): per-channel constant bias cancels in InstanceNorm mean.
  float* out = (float*)d_out;
  char* ws = (char*)d_ws;

  float* kernbuf = (float*)(ws);                 // 8*9*4096*4   = 0x120000
  short* Ws1     = (short*)(ws + 0x120000);      // 2*36*8192*2  = 0x120000
  short* Ws2     = (short*)(ws + 0x240000);      // 1*36*8192*2  = 0x090000
  float* mr1     = (float*)(ws + 0x2D0000);      // 2048*2*4
  float* mr2     = (float*)(ws + 0x2D4000);      // 1024*2*4
  float* pac     = (float*)(ws + 0x300000);      // 8*256*4096*4 = 0x2000000
  float* ybuf    = (float*)(ws + 0x2300000);     // 8*128*4096*4 = 0x1000000

  wconv_k<<<(256 * 2304 + 255) / 256, 256, 0, stream>>>(pac_w, Ws1, 256);
  wconv_k<<<(128 * 2304 + 255) / 256, 256, 0, stream>>>(dec_w, Ws2, 128);
  kern_k<<<dim3(64, 8), 256, 0, stream>>>(guide, kernbuf);

  gemm_conv<2, true, false><<<dim3(32, 2, 8), 512, 0, stream>>>(
      Ws1, feat, kernbuf, nullptr, pac);
  reduce_mv<<<8 * 256, 256, 0, stream>>>(pac, mr1);
  gemm_conv<1, false, true><<<dim3(32, 1, 8), 512, 0, stream>>>(
      Ws2, pac, nullptr, mr1, ybuf);
  reduce_mv<<<8 * 128, 256, 0, stream>>>(ybuf, mr2);
  finalize_k<<<4096, 256, 0, stream>>>(ybuf, mr2, out);
}